// Round 9
// baseline (86.834 us; speedup 1.0000x reference)
//
#include <hip/hip_runtime.h>
#include <hip/hip_bf16.h>

constexpr int HID = 1024;
constexpr int KD  = 16;    // probe directions
constexpr int TM  = 16;    // rows per wave-tile

typedef short bf16x8 __attribute__((ext_vector_type(8)));   // MFMA A/B frag
typedef float f32x4  __attribute__((ext_vector_type(4)));   // MFMA C/D frag

__device__ __forceinline__ short f2b(float x) {
    __hip_bfloat16 b = __float2bfloat16(x);
    return *reinterpret_cast<short*>(&b);
}

// ---- setup: pre-transpose + pre-convert Q into workspace (runs once per launch) ----
// Qt[r][k] = bf16(Q[k][r])  (16 x 1024)  -> coef-GEMM B-frags become 16B contiguous reads
// Qa[c][d] = bf16(Q[c][d])  (1024 x 16)  -> epilogue A-frags become 16B contiguous reads
__global__ void q_setup(const float* __restrict__ Qf,
                        short* __restrict__ Qt, short* __restrict__ Qa) {
    const int idx = blockIdx.x*256 + threadIdx.x;    // grid 64x256 = 16384
    if (idx < 16*HID) {
        const int r = idx >> 10, k = idx & 1023;
        Qt[idx] = f2b(Qf[k*KD + r]);
        Qa[idx] = f2b(Qf[idx]);
    }
}

// Round-8 diagnosis: block-cooperative barriers convoy all waves -> too few
// memory requests in flight -> 2.6 TB/s. This kernel has ZERO __syncthreads:
// one wave owns one 16-row tile end-to-end (full K=1024 coef GEMM, in-wave
// transpose via wave-PRIVATE LDS -- ds_write/ds_read in the same wave only
// needs lgkmcnt, no barrier -- then the epilogue GEMM + paired stores).
__global__ __launch_bounds__(256)
void probe_removal_wave(const float* __restrict__ H,
                        const short* __restrict__ Qt,
                        const short* __restrict__ Qa,
                        float* __restrict__ out, int ntiles)
{
    const int lane = threadIdx.x & 63;
    const int wv   = threadIdx.x >> 6;          // wave within block (0..3)
    const int r    = lane & 15;
    const int q    = lane >> 4;
    const int tile = blockIdx.x*4 + wv;
    if (tile >= ntiles) return;

    __shared__ __align__(16) float ctr[4][TM][20];   // wave-private C-transpose tiles

    const float* hrow  = H  + (size_t)tile*TM*HID + r*HID;   // this lane's row (f32)
    const short* qtrow = Qt + r*1024;

    // ---- coef GEMM: C[row][dir] = H_tile x Q over K=1024 (32 chunks) ----
    // A-frag: lane(r,q) holds H[r][kt*32+q*8 .. +7]; loads cover 16 rows x 128B
    // full lines per inst. Two accumulators break the serial MFMA dep chain.
    f32x4 acc0 = {0.f,0.f,0.f,0.f}, acc1 = {0.f,0.f,0.f,0.f};
    float s2 = 0.f;
    #pragma unroll 8
    for (int kt = 0; kt < 32; ++kt) {
        const float4 x = *reinterpret_cast<const float4*>(hrow + kt*32 + q*8);
        const float4 y = *reinterpret_cast<const float4*>(hrow + kt*32 + q*8 + 4);
        s2 = fmaf(x.x,x.x, fmaf(x.y,x.y, fmaf(x.z,x.z, fmaf(x.w,x.w, s2))));
        s2 = fmaf(y.x,y.x, fmaf(y.y,y.y, fmaf(y.z,y.z, fmaf(y.w,y.w, s2))));
        bf16x8 af;
        af[0]=f2b(x.x); af[1]=f2b(x.y); af[2]=f2b(x.z); af[3]=f2b(x.w);
        af[4]=f2b(y.x); af[5]=f2b(y.y); af[6]=f2b(y.z); af[7]=f2b(y.w);
        const bf16x8 bq = *reinterpret_cast<const bf16x8*>(qtrow + kt*32 + q*8);
        if (kt & 1) acc1 = __builtin_amdgcn_mfma_f32_16x16x32_bf16(af, bq, acc1, 0, 0, 0);
        else        acc0 = __builtin_amdgcn_mfma_f32_16x16x32_bf16(af, bq, acc0, 0, 0, 0);
    }
    const f32x4 acc = acc0 + acc1;
    s2 += __shfl_xor(s2, 16);          // combine q-groups -> s2[row r] at all lanes
    s2 += __shfl_xor(s2, 32);

    // ---- in-wave transpose: C layout (lane(r,q) holds C[q*4+i][r]) -> cf[r][dir] ----
    #pragma unroll
    for (int i = 0; i < 4; ++i) ctr[wv][q*4 + i][r] = acc[i];
    // (compiler inserts lgkmcnt wait; same-wave LDS -> no barrier needed)
    float cf[8] = {0,0,0,0,0,0,0,0};
    if (q < 2) {
        const float4 a = *reinterpret_cast<const float4*>(&ctr[wv][r][q*8]);
        const float4 b = *reinterpret_cast<const float4*>(&ctr[wv][r][q*8 + 4]);
        cf[0]=a.x; cf[1]=a.y; cf[2]=a.z; cf[3]=a.w;
        cf[4]=b.x; cf[5]=b.y; cf[6]=b.z; cf[7]=b.w;
    }
    float sc2 = 0.f;
    #pragma unroll
    for (int i = 0; i < 8; ++i) sc2 = fmaf(cf[i], cf[i], sc2);
    sc2 += __shfl_xor(sc2, 16);        // q0+q1 (q2,q3 contribute 0)
    sc2 += __shfl_xor(sc2, 32);
    const float scale = rsqrtf(fmaxf(1.0f - sc2 / s2, 1e-20f));

    bf16x8 pb;   // B[k=dir][n=row=r]; q>=2 lanes hold K-pad zeros
    #pragma unroll
    for (int i = 0; i < 8; ++i) pb[i] = f2b(cf[i]);

    // ---- epilogue: D^T = Q x C^T per 16-col tile; out = (h - D)*scale ----
    // j-pairs computed together; their two stores (adjacent 64B halves of the
    // same 128B lines) issue back-to-back so L2 merges them into full lines.
    float* orow = out + (size_t)tile*TM*HID + r*HID;
    const f32x4 zero4 = {0.f,0.f,0.f,0.f};
    #pragma unroll 4
    for (int jp = 0; jp < 32; ++jp) {
        const int j0 = jp*2, j1 = jp*2 + 1;
        bf16x8 a0, a1;
        if (q < 2) {
            a0 = *reinterpret_cast<const bf16x8*>(Qa + (j0*16 + r)*KD + q*8);
            a1 = *reinterpret_cast<const bf16x8*>(Qa + (j1*16 + r)*KD + q*8);
        } else {
            #pragma unroll
            for (int i = 0; i < 8; ++i) { a0[i] = 0; a1[i] = 0; }
        }
        const f32x4 d0 = __builtin_amdgcn_mfma_f32_16x16x32_bf16(a0, pb, zero4, 0, 0, 0);
        const f32x4 d1 = __builtin_amdgcn_mfma_f32_16x16x32_bf16(a1, pb, zero4, 0, 0, 0);
        // lane(r,q) holds out[row r][cols j*16 + q*4 + 0..3]; h re-read is L2/L3-hot
        const float4 h0 = *reinterpret_cast<const float4*>(hrow + j0*16 + q*4);
        const float4 h1 = *reinterpret_cast<const float4*>(hrow + j1*16 + q*4);
        f32x4 o0, o1;
        o0[0]=(h0.x-d0[0])*scale; o0[1]=(h0.y-d0[1])*scale;
        o0[2]=(h0.z-d0[2])*scale; o0[3]=(h0.w-d0[3])*scale;
        o1[0]=(h1.x-d1[0])*scale; o1[1]=(h1.y-d1[1])*scale;
        o1[2]=(h1.z-d1[2])*scale; o1[3]=(h1.w-d1[3])*scale;
        __builtin_nontemporal_store(o0, reinterpret_cast<f32x4*>(orow + j0*16 + q*4));
        __builtin_nontemporal_store(o1, reinterpret_cast<f32x4*>(orow + j1*16 + q*4));
    }
}

extern "C" void kernel_launch(void* const* d_in, const int* in_sizes, int n_in,
                              void* d_out, int out_size, void* d_ws, size_t ws_size,
                              hipStream_t stream) {
    const float* H  = (const float*)d_in[0];   // [8,4096,1024] f32
    const float* Qf = (const float*)d_in[1];   // [1024,16] f32, orthonormal cols
    float* outp     = (float*)d_out;
    const int nrows  = in_sizes[0] / HID;      // 32768
    const int ntiles = nrows / TM;             // 2048

    short* Qt = (short*)d_ws;                  // 32 KB
    short* Qa = Qt + 16*HID;                   // 32 KB

    hipLaunchKernelGGL(q_setup, dim3(64), dim3(256), 0, stream, Qf, Qt, Qa);

    // one wave per tile: 2048 independent waves, no intra-kernel barriers
    const int nblocks = (ntiles + 3) / 4;      // 512 blocks x 4 waves
    hipLaunchKernelGGL(probe_removal_wave, dim3(nblocks), dim3(256), 0, stream,
                       H, Qt, Qa, outp, ntiles);
}

// Round 10
// 72.914 us; speedup vs baseline: 1.1909x; 1.1909x over previous
//
#include <hip/hip_runtime.h>
#include <hip/hip_bf16.h>

constexpr int HID = 1024;
constexpr int KD  = 16;    // probe directions
constexpr int TM  = 16;    // rows per tile
constexpr int NW  = 4;     // waves per block (each owns a 256-wide K slice)

typedef short bf16x8 __attribute__((ext_vector_type(8)));   // MFMA A/B frag
typedef float f32x4  __attribute__((ext_vector_type(4)));   // MFMA C/D frag

__device__ __forceinline__ short f2b(float x) {
    __hip_bfloat16 b = __float2bfloat16(x);
    return *reinterpret_cast<short*>(&b);
}

// ---- setup: pre-transpose + pre-convert Q into workspace ----
// Qt[r][k] = bf16(Q[k][r])  (16 x 1024): coef B-frags = 16B contiguous reads
// Qa[c][d] = bf16(Q[c][d])  (1024 x 16): epilogue A-frags = 16B contiguous reads
__global__ void q_setup(const float* __restrict__ Qf,
                        short* __restrict__ Qt, short* __restrict__ Qa) {
    const int idx = blockIdx.x*256 + threadIdx.x;
    if (idx < 16*HID) {
        const int r = idx >> 10, k = idx & 1023;
        Qt[idx] = f2b(Qf[k*KD + r]);
        Qa[idx] = f2b(Qf[idx]);
    }
}

// Round-9 post-mortem: 1 wave/tile = 2 waves/SIMD occupancy famine; nt stores
// defeated L2 half-line merging. This version: 4 waves split one tile's K,
// ONE __syncthreads total, 2048 independent blocks -> 8 waves/SIMD with
// co-resident blocks at uncorrelated phases (no convoy), plain stores so L2
// write-back emits full 128B lines.
__global__ __launch_bounds__(NW*64)
void probe_removal_w4(const float* __restrict__ H,
                      const short* __restrict__ Qt,
                      const short* __restrict__ Qa,
                      float* __restrict__ out)
{
    const int lane = threadIdx.x & 63;
    const int w    = threadIdx.x >> 6;   // wave 0..3: K-slice [w*256, w*256+256)
    const int r    = lane & 15;
    const int q    = lane >> 4;
    const int tile = blockIdx.x;

    __shared__ __align__(16) float ctr[NW][TM][20];  // C partials [wave][row][dir]
    __shared__ float s2p[NW][TM];                    // ||h||^2 partials

    const float* hrow = H + (size_t)tile*TM*HID + r*HID;   // lane's row (f32)

    // ---- coef GEMM: this wave's 256-wide K slice (8 MFMAs, 2 accumulators) ----
    f32x4 acc0 = {0.f,0.f,0.f,0.f}, acc1 = {0.f,0.f,0.f,0.f};
    float s2 = 0.f;
    #pragma unroll
    for (int kt = 0; kt < 8; ++kt) {
        const int col = w*256 + kt*32 + q*8;
        const float4 x = *reinterpret_cast<const float4*>(hrow + col);
        const float4 y = *reinterpret_cast<const float4*>(hrow + col + 4);
        s2 = fmaf(x.x,x.x, fmaf(x.y,x.y, fmaf(x.z,x.z, fmaf(x.w,x.w, s2))));
        s2 = fmaf(y.x,y.x, fmaf(y.y,y.y, fmaf(y.z,y.z, fmaf(y.w,y.w, s2))));
        bf16x8 af;
        af[0]=f2b(x.x); af[1]=f2b(x.y); af[2]=f2b(x.z); af[3]=f2b(x.w);
        af[4]=f2b(y.x); af[5]=f2b(y.y); af[6]=f2b(y.z); af[7]=f2b(y.w);
        const bf16x8 bq = *reinterpret_cast<const bf16x8*>(Qt + r*1024 + col);
        if (kt & 1) acc1 = __builtin_amdgcn_mfma_f32_16x16x32_bf16(af, bq, acc1, 0, 0, 0);
        else        acc0 = __builtin_amdgcn_mfma_f32_16x16x32_bf16(af, bq, acc0, 0, 0, 0);
    }
    const f32x4 acc = acc0 + acc1;
    s2 += __shfl_xor(s2, 16);          // combine q-groups: s2 partial for row r
    s2 += __shfl_xor(s2, 32);

    #pragma unroll
    for (int i = 0; i < 4; ++i) ctr[w][q*4 + i][r] = acc[i];   // C[m=q*4+i][n=dir=r]
    if (q == 0) s2p[w][r] = s2;

    __syncthreads();   // the ONLY barrier in the kernel

    // ---- reduce over the 4 waves -> coefs for row r, scale ----
    float cf[8] = {0,0,0,0,0,0,0,0};
    if (q < 2) {
        #pragma unroll
        for (int w2 = 0; w2 < NW; ++w2) {
            const float4 a = *reinterpret_cast<const float4*>(&ctr[w2][r][q*8]);
            const float4 b = *reinterpret_cast<const float4*>(&ctr[w2][r][q*8 + 4]);
            cf[0]+=a.x; cf[1]+=a.y; cf[2]+=a.z; cf[3]+=a.w;
            cf[4]+=b.x; cf[5]+=b.y; cf[6]+=b.z; cf[7]+=b.w;
        }
    }
    float s2tot = 0.f;
    #pragma unroll
    for (int w2 = 0; w2 < NW; ++w2) s2tot += s2p[w2][r];   // broadcast reads

    float sc2 = 0.f;
    #pragma unroll
    for (int i = 0; i < 8; ++i) sc2 = fmaf(cf[i], cf[i], sc2);
    sc2 += __shfl_xor(sc2, 16);
    sc2 += __shfl_xor(sc2, 32);
    const float scale = rsqrtf(fmaxf(1.0f - sc2 / s2tot, 1e-20f));

    bf16x8 pb;   // B[k=dir][n=row=r]; q>=2 lanes carry the K-pad zeros
    #pragma unroll
    for (int i = 0; i < 8; ++i) pb[i] = f2b(cf[i]);

    // ---- epilogue: wave w covers cols [w*256, w*256+256) = 16 col-tiles ----
    float* orow = out + (size_t)tile*TM*HID + r*HID;
    const f32x4 zero4 = {0.f,0.f,0.f,0.f};
    #pragma unroll 4
    for (int jj = 0; jj < 16; ++jj) {
        const int j = w*16 + jj;
        bf16x8 aj;
        if (q < 2) {
            aj = *reinterpret_cast<const bf16x8*>(Qa + (j*16 + r)*KD + q*8);
        } else {
            #pragma unroll
            for (int i = 0; i < 8; ++i) aj[i] = 0;
        }
        const f32x4 d = __builtin_amdgcn_mfma_f32_16x16x32_bf16(aj, pb, zero4, 0, 0, 0);
        // lane(r,q) holds out[row r][j*16 + q*4 + 0..3]; h re-read is L2-hot
        const float4 hx = *reinterpret_cast<const float4*>(hrow + j*16 + q*4);
        f32x4 o;
        o[0] = (hx.x - d[0]) * scale;
        o[1] = (hx.y - d[1]) * scale;
        o[2] = (hx.z - d[2]) * scale;
        o[3] = (hx.w - d[3]) * scale;
        // plain store (NOT nontemporal): L2 write-back merges the four 64B
        // quads of each 128B line into full-line HBM writes
        *reinterpret_cast<f32x4*>(orow + j*16 + q*4) = o;
    }
}

extern "C" void kernel_launch(void* const* d_in, const int* in_sizes, int n_in,
                              void* d_out, int out_size, void* d_ws, size_t ws_size,
                              hipStream_t stream) {
    const float* H  = (const float*)d_in[0];   // [8,4096,1024] f32
    const float* Qf = (const float*)d_in[1];   // [1024,16] f32, orthonormal cols
    float* outp     = (float*)d_out;
    const int nrows  = in_sizes[0] / HID;      // 32768
    const int ntiles = nrows / TM;             // 2048

    short* Qt = (short*)d_ws;                  // 32 KB
    short* Qa = Qt + 16*HID;                   // 32 KB

    hipLaunchKernelGGL(q_setup, dim3(64), dim3(256), 0, stream, Qf, Qt, Qa);

    // one 16-row tile per 4-wave block; 2048 blocks -> 8192 waves (8/SIMD)
    hipLaunchKernelGGL(probe_removal_w4, dim3(ntiles), dim3(NW*64), 0, stream,
                       H, Qt, Qa, outp);
}